// Round 2
// baseline (421.636 us; speedup 1.0000x reference)
//
#include <hip/hip_runtime.h>

typedef __bf16 bf16x8 __attribute__((ext_vector_type(8)));
typedef float f32x16 __attribute__((ext_vector_type(16)));
typedef float f32x4 __attribute__((ext_vector_type(4)));
typedef unsigned int u32;
typedef unsigned int u32x4 __attribute__((ext_vector_type(4)));
typedef unsigned int u32x2 __attribute__((ext_vector_type(2)));
typedef unsigned short u16;
typedef unsigned short u16x4 __attribute__((ext_vector_type(4)));
typedef unsigned short u16x8 __attribute__((ext_vector_type(8)));

#define DEV static __device__ __forceinline__

DEV u16 f2bf(float f){
  unsigned u = __float_as_uint(f);
  u += 0x7FFFu + ((u >> 16) & 1u);   // round-to-nearest-even
  return (u16)(u >> 16);
}
DEV float bf2f(u16 h){ return __uint_as_float(((u32)h) << 16); }

constexpr int BATCH = 4, LQ = 4096, SK = 4096, DH = 256, BL = BATCH * LQ;
constexpr int NQUART = 4;                 // KV split for occupancy
constexpr int ITERS = SK / NQUART / 64;   // 16 KV-tiles of 64 per block

// ---------------------------------------------------------------------------
// Weight transpose + f32->bf16 cast: src[R][C] -> dst[C][R]
// ---------------------------------------------------------------------------
__global__ void transpose_cvt(const float* __restrict__ src, u16* __restrict__ dst,
                              int R, int C){
  int idx = blockIdx.x * 256 + threadIdx.x;
  if (idx >= R * C) return;
  int r = idx / C, c = idx - r * C;
  dst[(size_t)c * R + r] = f2bf(src[idx]);
}

// source f32 [BL,256] -> hcat bf16 [BL,512] left half
__global__ void cvt_src(const float* __restrict__ src, u16* __restrict__ hcat){
  int idx = blockIdx.x * 256 + threadIdx.x;   // BL*32 total, 8 elems each
  int row = idx >> 5, c = (idx & 31) * 8;
  const float* p = src + (size_t)row * DH + c;
  f32x4 a = *(const f32x4*)p;
  f32x4 b = *(const f32x4*)(p + 4);
  u16x8 h;
  h[0]=f2bf(a[0]); h[1]=f2bf(a[1]); h[2]=f2bf(a[2]); h[3]=f2bf(a[3]);
  h[4]=f2bf(b[0]); h[5]=f2bf(b[1]); h[6]=f2bf(b[2]); h[7]=f2bf(b[3]);
  *(u16x8*)&hcat[(size_t)row * 512 + c] = h;
}

// ---------------------------------------------------------------------------
// GEMM: A[M,K] (f32 or bf16) @ W (given as WT bf16 [N,K]) -> out, BM=BN=128 BK=64
// EPI: 0 = bf16 out, (acc+bias)*scale   (q / k)
//      1 = bf16 out transposed to [B,DH,SK] (v^T), +bias
//      2 = f32 out, +bias (nullable)
//      3 = bf16 out, exact GELU, no bias
// ---------------------------------------------------------------------------
template<bool A_F32, int EPI>
__global__ __launch_bounds__(256, 2) void gemm128(
  const void* __restrict__ Ap, const u16* __restrict__ BTp,
  const float* __restrict__ bias, void* __restrict__ outp,
  int M, int N, int K, float scale)
{
  __shared__ u16 A_lds[128 * 64];
  __shared__ u16 B_lds[128 * 64];
  const int tid = threadIdx.x, lane = tid & 63, wid = tid >> 6;
  const int ql = lane & 31, g = lane >> 5;
  const int m0 = blockIdx.y * 128, n0 = blockIdx.x * 128;
  const int mr = (wid & 1) * 64, nr = (wid >> 1) * 64;

  f32x16 acc[2][2] = {};
  f32x4 afreg[8];
  u32x4 abreg[4];
  u32x4 breg[4];
  const float* Af = (const float*)Ap;
  const u16*   Ab = (const u16*)Ap;

#define G_LOAD_A(kb) do { \
    if constexpr (A_F32) { \
      _Pragma("unroll") \
      for (int i = 0; i < 8; i++){ int item = tid + i*256; int r = item>>4, c = (item&15)*4; \
        afreg[i] = *(const f32x4*)&Af[(size_t)(m0+r)*K + (kb)*64 + c]; } \
    } else { \
      _Pragma("unroll") \
      for (int i = 0; i < 4; i++){ int item = tid + i*256; int r = item>>3, c = (item&7)*8; \
        abreg[i] = *(const u32x4*)&Ab[(size_t)(m0+r)*K + (kb)*64 + c]; } \
    } \
  } while(0)
#define G_LOAD_B(kb) do { \
    _Pragma("unroll") \
    for (int i = 0; i < 4; i++){ int item = tid + i*256; int r = item>>3, c = (item&7)*8; \
      breg[i] = *(const u32x4*)&BTp[(size_t)(n0+r)*K + (kb)*64 + c]; } \
  } while(0)

  G_LOAD_A(0); G_LOAD_B(0);

  const int nkb = K >> 6;
  for (int kb = 0; kb < nkb; ++kb){
    __syncthreads();
    if constexpr (A_F32){
      #pragma unroll
      for (int i = 0; i < 8; i++){ int item = tid + i*256; int r = item>>4, c = (item&15)*4;
        u16x4 h; h[0]=f2bf(afreg[i][0]); h[1]=f2bf(afreg[i][1]);
                 h[2]=f2bf(afreg[i][2]); h[3]=f2bf(afreg[i][3]);
        *(u16x4*)&A_lds[r*64 + (c ^ ((r&7)*8))] = h; }
    } else {
      #pragma unroll
      for (int i = 0; i < 4; i++){ int item = tid + i*256; int r = item>>3, c = (item&7)*8;
        *(u32x4*)&A_lds[r*64 + (c ^ ((r&7)*8))] = abreg[i]; }
    }
    #pragma unroll
    for (int i = 0; i < 4; i++){ int item = tid + i*256; int r = item>>3, c = (item&7)*8;
      *(u32x4*)&B_lds[r*64 + (c ^ ((r&7)*8))] = breg[i]; }
    __syncthreads();
    if (kb + 1 < nkb){ G_LOAD_A(kb+1); G_LOAD_B(kb+1); }

    #pragma unroll
    for (int kk = 0; kk < 4; kk++){
      bf16x8 af[2], bf[2];
      #pragma unroll
      for (int mi = 0; mi < 2; mi++)
        af[mi] = __builtin_bit_cast(bf16x8,
          *(const u32x4*)&A_lds[(mr+mi*32+ql)*64 + ((kk*16+g*8) ^ ((ql&7)*8))]);
      #pragma unroll
      for (int ni = 0; ni < 2; ni++)
        bf[ni] = __builtin_bit_cast(bf16x8,
          *(const u32x4*)&B_lds[(nr+ni*32+ql)*64 + ((kk*16+g*8) ^ ((ql&7)*8))]);
      #pragma unroll
      for (int mi = 0; mi < 2; mi++)
        #pragma unroll
        for (int ni = 0; ni < 2; ni++)
          acc[mi][ni] = __builtin_amdgcn_mfma_f32_32x32x16_bf16(af[mi], bf[ni], acc[mi][ni], 0, 0, 0);
    }
  }

  #pragma unroll
  for (int mi = 0; mi < 2; mi++){
    #pragma unroll
    for (int ni = 0; ni < 2; ni++){
      const int col = n0 + nr + ni*32 + ql;
      const float bv = bias ? bias[col] : 0.f;
      if constexpr (EPI == 1){
        #pragma unroll
        for (int qd = 0; qd < 4; qd++){
          u16x4 h;
          #pragma unroll
          for (int i = 0; i < 4; i++) h[i] = f2bf(acc[mi][ni][qd*4+i] + bv);
          int row0 = m0 + mr + mi*32 + qd*8 + 4*g;
          int bb = row0 >> 12, ss = row0 & 4095;
          *(u16x4*)&((u16*)outp)[((size_t)bb*DH + col)*SK + ss] = h;
        }
      } else {
        #pragma unroll
        for (int j = 0; j < 16; j++){
          int row = m0 + mr + mi*32 + (j&3) + 8*(j>>2) + 4*g;
          float v = acc[mi][ni][j] + bv;
          if constexpr (EPI == 0){
            ((u16*)outp)[(size_t)row*N + col] = f2bf(v * scale);
          } else if constexpr (EPI == 2){
            ((float*)outp)[(size_t)row*N + col] = v;
          } else {
            v = 0.5f * v * (1.f + erff(v * 0.70710678118f));
            ((u16*)outp)[(size_t)row*N + col] = f2bf(v);
          }
        }
      }
    }
  }
}

// ---------------------------------------------------------------------------
// Flash attention. grid (LQ/128, BATCH, NQUART), 256 threads (4 waves).
// Wave owns 32 q-rows. Swapped QK^T: scores^T = mfma(K, Q) -> lane owns
// q-col = lane&31. P stays IN REGISTER: cvt_pk_bf16 + permlane32_swap builds
// the PV B-fragments directly (T12 adaptation). PV: O^T = mfma(V^T, P).
// q pre-scaled by log2(e)/sqrt(D); softmax in exp2 domain; defer-max (THR=8).
// LDS = 64 KB -> 2 blocks/CU with VGPR<=256.
// ---------------------------------------------------------------------------
__global__ __launch_bounds__(256, 2) void attn_kernel(
  const u16* __restrict__ qb, const u16* __restrict__ kb,
  const u16* __restrict__ vtb, u16* __restrict__ opart, float* __restrict__ stats)
{
  __shared__ u16 K_lds[64 * 256];    // [s][d]  xor-swizzled (16B granule)
  __shared__ u16 VT_lds[256 * 64];   // [d][s]  xor-swizzled

  const int tid = threadIdx.x;
  const int wid = tid >> 6, lane = tid & 63;
  const int ql = lane & 31, g = lane >> 5;
  const int b = blockIdx.y, quart = blockIdx.z;
  const int qrow0 = blockIdx.x * 128 + wid * 32;
  const int s0base = quart * (SK / NQUART);

  bf16x8 qf[16];
  {
    const u16* qp = qb + ((size_t)(b*LQ + qrow0 + ql)) * DH + g * 8;
    #pragma unroll
    for (int kk = 0; kk < 16; kk++)
      qf[kk] = __builtin_bit_cast(bf16x8, *(const u32x4*)(qp + kk*16));
  }

  const u16* kbase = kb  + (size_t)b * SK * DH;
  const u16* vbase = vtb + (size_t)b * DH * SK;

  u32x4 kreg[8], vreg[8];
#define LOAD_TILES(s0) do { \
    _Pragma("unroll") \
    for (int i = 0; i < 8; i++){ int grp = tid + i*256; int s = grp>>5, dc = (grp&31)*8; \
      kreg[i] = *(const u32x4*)(kbase + (size_t)((s0)+s)*DH + dc); } \
    _Pragma("unroll") \
    for (int i = 0; i < 8; i++){ int grp = tid + i*256; int d = grp>>3, sc = (grp&7)*8; \
      vreg[i] = *(const u32x4*)(vbase + (size_t)d*SK + (s0) + sc); } \
  } while(0)

  LOAD_TILES(s0base);

  f32x16 accO[8] = {};
  float m_run = -1e30f, l_run = 0.f;

  for (int it = 0; it < ITERS; ++it){
    __syncthreads();
    #pragma unroll
    for (int i = 0; i < 8; i++){ int grp = tid + i*256; int s = grp>>5, dc = (grp&31)*8;
      *(u32x4*)&K_lds[s*256 + (dc ^ ((s&7)*8))] = kreg[i]; }
    #pragma unroll
    for (int i = 0; i < 8; i++){ int grp = tid + i*256; int d = grp>>3, sc = (grp&7)*8;
      *(u32x4*)&VT_lds[d*64 + (sc ^ ((d&7)*8))] = vreg[i]; }
    __syncthreads();
    if (it + 1 < ITERS) LOAD_TILES(s0base + (it+1)*64);

    // QK^T (swapped): ps[st] holds scores for q=lane&31, s=st*32+(j&3)+8*(j>>2)+4g
    f32x16 ps[2];
    __builtin_amdgcn_s_setprio(1);
    #pragma unroll
    for (int st = 0; st < 2; ++st){
      f32x16 a = {};
      #pragma unroll
      for (int kk = 0; kk < 16; ++kk){
        bf16x8 kf = __builtin_bit_cast(bf16x8,
          *(const u32x4*)&K_lds[(st*32+ql)*256 + ((kk*16 + g*8) ^ ((ql&7)*8))]);
        a = __builtin_amdgcn_mfma_f32_32x32x16_bf16(kf, qf[kk], a, 0, 0, 0);
      }
      ps[st] = a;
    }
    __builtin_amdgcn_s_setprio(0);

    // online softmax (exp2 domain) with defer-max
    float vmax = -1e30f;
    #pragma unroll
    for (int st = 0; st < 2; st++)
      #pragma unroll
      for (int j = 0; j < 16; j++) vmax = fmaxf(vmax, ps[st][j]);
    vmax = fmaxf(vmax, __shfl_xor(vmax, 32, 64));
    if (!__all(vmax <= m_run + 8.0f)){
      float m_new = fmaxf(m_run, vmax);
      float alpha = exp2f(m_run - m_new);
      l_run *= alpha;
      #pragma unroll
      for (int dt = 0; dt < 8; dt++)
        #pragma unroll
        for (int j = 0; j < 16; j++) accO[dt][j] *= alpha;
      m_run = m_new;
    }
    float psum = 0.f;
    #pragma unroll
    for (int st = 0; st < 2; st++)
      #pragma unroll
      for (int j = 0; j < 16; j++){ float p = exp2f(ps[st][j] - m_run); ps[st][j] = p; psum += p; }
    psum += __shfl_xor(psum, 32, 64);
    l_run += psum;

    // in-register P -> PV B-fragments (cvt_pk + permlane32_swap).
    // packed word Wp[st][qd][h] = bf16 pair (s = st*32+qd*8+4g+2h, +1) for q=ql.
    u32 Wp[2][4][2];
    #pragma unroll
    for (int st = 0; st < 2; st++)
      #pragma unroll
      for (int qd = 0; qd < 4; qd++)
        #pragma unroll
        for (int h = 0; h < 2; h++){
          float lo = ps[st][qd*4 + 2*h], hi = ps[st][qd*4 + 2*h + 1];
          asm("v_cvt_pk_bf16_f32 %0, %1, %2" : "=v"(Wp[st][qd][h]) : "v"(lo), "v"(hi));
        }
    bf16x8 pf[4];
    #pragma unroll
    for (int ks = 0; ks < 4; ks++){
      const int st = ks >> 1, qp = (ks & 1) * 2;
      u32 a0 = Wp[st][qp][0], b0 = Wp[st][qp+1][0];
      u32 a1 = Wp[st][qp][1], b1 = Wp[st][qp+1][1];
      asm("v_permlane32_swap_b32 %0, %1" : "+v"(a0), "+v"(b0));
      asm("v_permlane32_swap_b32 %0, %1" : "+v"(a1), "+v"(b1));
      u32x4 w; w[0] = a0; w[1] = a1; w[2] = b0; w[3] = b1;
      pf[ks] = __builtin_bit_cast(bf16x8, w);
    }

    // PV: O^T += mfma(VT, P)
    __builtin_amdgcn_s_setprio(1);
    #pragma unroll
    for (int dt = 0; dt < 8; dt++){
      #pragma unroll
      for (int ks = 0; ks < 4; ks++){
        bf16x8 vf = __builtin_bit_cast(bf16x8,
          *(const u32x4*)&VT_lds[(dt*32+ql)*64 + ((ks*16 + g*8) ^ ((ql&7)*8))]);
        accO[dt] = __builtin_amdgcn_mfma_f32_32x32x16_bf16(vf, pf[ks], accO[dt], 0, 0, 0);
      }
    }
    __builtin_amdgcn_s_setprio(0);
  }

  __syncthreads();   // all waves done with K_lds before scratch aliasing

  const int rowb = b * LQ + qrow0;
  if (g == 0){
    stats[(size_t)(quart*2 + 0)*BL + rowb + ql] = m_run;
    stats[(size_t)(quart*2 + 1)*BL + rowb + ql] = l_run;
  }

  // transpose O^T -> row-major via LDS scratch aliased onto K_lds; bf16 store
  float* scratch = (float*)&K_lds[wid * 2112];   // 32x33 f32 per wave
  #pragma unroll
  for (int dt = 0; dt < 8; dt++){
    #pragma unroll
    for (int j = 0; j < 16; j++){
      int dl = (j&3) + 8*(j>>2) + 4*g;
      scratch[ql*33 + dl] = accO[dt][j];
    }
    int q2 = lane >> 1, dl2 = (lane & 1) * 16;
    u16x8 h0, h1;
    #pragma unroll
    for (int i = 0; i < 8; i++){ h0[i] = f2bf(scratch[q2*33 + dl2 + i]);
                                 h1[i] = f2bf(scratch[q2*33 + dl2 + 8 + i]); }
    u16* op = &opart[((size_t)quart*BL + rowb + q2)*DH + dt*32 + dl2];
    *(u16x8*)op = h0;
    *(u16x8*)(op + 8) = h1;
  }
}

// combine the four KV-quarter partials -> message bf16
__global__ void merge_kernel(const u16* __restrict__ opart,
                             const float* __restrict__ stats, u16* __restrict__ msg){
  int gid = blockIdx.x * 256 + threadIdx.x;   // BL*32
  int row = gid >> 5, d0 = (gid & 31) * 8;
  float m[4], l[4];
  #pragma unroll
  for (int q = 0; q < 4; q++){
    m[q] = stats[(size_t)(q*2 + 0)*BL + row];
    l[q] = stats[(size_t)(q*2 + 1)*BL + row];
  }
  float mm = fmaxf(fmaxf(m[0], m[1]), fmaxf(m[2], m[3]));
  float w[4], denom = 0.f;
  #pragma unroll
  for (int q = 0; q < 4; q++){ w[q] = exp2f(m[q] - mm); denom += l[q]*w[q]; }
  float inv = 1.f / denom;
  float acc[8] = {};
  #pragma unroll
  for (int q = 0; q < 4; q++){
    u16x8 o = *(const u16x8*)&opart[((size_t)q*BL + row)*DH + d0];
    #pragma unroll
    for (int i = 0; i < 8; i++) acc[i] += bf2f(o[i]) * w[q];
  }
  u16x8 h;
  #pragma unroll
  for (int i = 0; i < 8; i++) h[i] = f2bf(acc[i] * inv);
  *(u16x8*)&msg[(size_t)row*DH + d0] = h;
}

// LayerNorm over D=256. OMODE 0: bf16 -> hcat[:,256:512]. OMODE 1: f32 out = src + LN(x).
template<int OMODE>
__global__ void ln_kernel(const float* __restrict__ x, const float* __restrict__ gamma,
                          const float* __restrict__ beta, const float* __restrict__ src,
                          void* __restrict__ outp){
  int wid = threadIdx.x >> 6, lane = threadIdx.x & 63;
  int row = blockIdx.x * 4 + wid;
  const float* xr = x + (size_t)row * DH;
  f32x4 v = *(const f32x4*)&xr[lane*4];
  float s1 = v[0]+v[1]+v[2]+v[3];
  float s2 = v[0]*v[0]+v[1]*v[1]+v[2]*v[2]+v[3]*v[3];
  #pragma unroll
  for (int m = 1; m < 64; m <<= 1){ s1 += __shfl_xor(s1, m, 64); s2 += __shfl_xor(s2, m, 64); }
  float mu = s1 * (1.f/DH);
  float var = s2 * (1.f/DH) - mu*mu;
  float rstd = rsqrtf(var + 1e-5f);
  f32x4 gv = *(const f32x4*)&gamma[lane*4];
  f32x4 bv = *(const f32x4*)&beta[lane*4];
  if constexpr (OMODE == 0){
    u16x4 h;
    #pragma unroll
    for (int i = 0; i < 4; i++) h[i] = f2bf((v[i]-mu)*rstd*gv[i] + bv[i]);
    *(u16x4*)&((u16*)outp)[(size_t)row*512 + 256 + lane*4] = h;
  } else {
    const float* sr = src + (size_t)row * DH;
    f32x4 s = *(const f32x4*)&sr[lane*4];
    f32x4 o;
    #pragma unroll
    for (int i = 0; i < 4; i++) o[i] = s[i] + (v[i]-mu)*rstd*gv[i] + bv[i];
    *(f32x4*)&((float*)outp)[(size_t)row*DH + lane*4] = o;
  }
}

// ---------------------------------------------------------------------------
extern "C" void kernel_launch(void* const* d_in, const int* in_sizes, int n_in,
                              void* d_out, int out_size, void* d_ws, size_t ws_size,
                              hipStream_t stream)
{
  const float* source = (const float*)d_in[0];
  const float* target = (const float*)d_in[1];
  const float* Wq = (const float*)d_in[2];  const float* bq = (const float*)d_in[3];
  const float* Wk = (const float*)d_in[4];  const float* bk = (const float*)d_in[5];
  const float* Wv = (const float*)d_in[6];  const float* bv = (const float*)d_in[7];
  const float* Wm = (const float*)d_in[8];  const float* bm = (const float*)d_in[9];
  const float* g1 = (const float*)d_in[10]; const float* be1 = (const float*)d_in[11];
  const float* W1 = (const float*)d_in[12]; const float* W2 = (const float*)d_in[13];
  const float* g2 = (const float*)d_in[14]; const float* be2 = (const float*)d_in[15];

  char* ws = (char*)d_ws;
  u16* WqT = (u16*)(ws);
  u16* WkT = (u16*)(ws + (size_t)(1u<<17));
  u16* WvT = (u16*)(ws + (size_t)2*(1u<<17));
  u16* WmT = (u16*)(ws + (size_t)3*(1u<<17));
  u16* W1T = (u16*)(ws + (size_t)4*(1u<<17));
  u16* W2T = (u16*)(ws + (size_t)4*(1u<<17) + (1u<<19));
  size_t off = (size_t)4*(1u<<17) + (1u<<19) + (1u<<18);   // 1,310,720
  u16* qbuf  = (u16*)(ws + off); off += (size_t)BL*DH*2;
  u16* kbuf  = (u16*)(ws + off); off += (size_t)BL*DH*2;
  u16* vtbuf = (u16*)(ws + off); off += (size_t)BL*DH*2;
  u16* msg   = (u16*)(ws + off); off += (size_t)BL*DH*2;
  u16* hcat  = (u16*)(ws + off); off += (size_t)BL*512*2;
  u16* hact  = (u16*)(ws + off); off += (size_t)BL*512*2;
  u16* opart = (u16*)(ws + off); off += (size_t)NQUART*BL*DH*2;  // bf16 partials
  float* stats = (float*)(ws + off); off += (size_t)2*NQUART*BL*4;
  float* msg2 = (float*)opart;  // alias: opart dead after merge
  float* h2   = (float*)qbuf;   // alias: q/k dead after attention (spans qbuf+kbuf)

  // prep: weight transposes (bf16) + source -> hcat left half
  transpose_cvt<<<dim3(256), 256, 0, stream>>>(Wq, WqT, 256, 256);
  transpose_cvt<<<dim3(256), 256, 0, stream>>>(Wk, WkT, 256, 256);
  transpose_cvt<<<dim3(256), 256, 0, stream>>>(Wv, WvT, 256, 256);
  transpose_cvt<<<dim3(256), 256, 0, stream>>>(Wm, WmT, 256, 256);
  transpose_cvt<<<dim3(1024), 256, 0, stream>>>(W1, W1T, 512, 512);
  transpose_cvt<<<dim3(512), 256, 0, stream>>>(W2, W2T, 512, 256);
  cvt_src<<<dim3(BL*32/256), 256, 0, stream>>>(source, hcat);

  // projections (q pre-scaled by log2(e)/sqrt(D) for exp2-domain softmax)
  const float qscale = 1.4426950408889634f / 16.0f;
  gemm128<true, 0><<<dim3(2, BL/128), 256, 0, stream>>>(source, WqT, bq, qbuf, BL, 256, 256, qscale);
  gemm128<true, 0><<<dim3(2, BL/128), 256, 0, stream>>>(target, WkT, bk, kbuf, BL, 256, 256, 1.0f);
  gemm128<true, 1><<<dim3(2, BL/128), 256, 0, stream>>>(target, WvT, bv, vtbuf, BL, 256, 256, 1.0f);

  // flash attention (4 KV quarters) + merge
  attn_kernel<<<dim3(LQ/128, BATCH, NQUART), 256, 0, stream>>>(qbuf, kbuf, vtbuf, opart, stats);
  merge_kernel<<<dim3(BL*32/256), 256, 0, stream>>>(opart, stats, msg);

  // output proj + LN1 -> hcat right half
  gemm128<false, 2><<<dim3(2, BL/128), 256, 0, stream>>>(msg, WmT, bm, msg2, BL, 256, 256, 1.0f);
  ln_kernel<0><<<dim3(BL/4), 256, 0, stream>>>(msg2, g1, be1, nullptr, hcat);

  // MLP: GELU(hcat @ W1) @ W2, LN2 + residual
  gemm128<false, 3><<<dim3(4, BL/128), 256, 0, stream>>>(hcat, W1T, nullptr, hact, BL, 512, 512, 1.0f);
  gemm128<false, 2><<<dim3(2, BL/128), 256, 0, stream>>>(hact, W2T, nullptr, h2, BL, 256, 512, 1.0f);
  ln_kernel<1><<<dim3(BL/4), 256, 0, stream>>>(h2, g2, be2, source, d_out);
}

// Round 3
// 234.717 us; speedup vs baseline: 1.7964x; 1.7964x over previous
//
#include <hip/hip_runtime.h>

typedef __bf16 bf16x8 __attribute__((ext_vector_type(8)));
typedef float f32x16 __attribute__((ext_vector_type(16)));
typedef float f32x4 __attribute__((ext_vector_type(4)));
typedef unsigned int u32;
typedef unsigned int u32x4 __attribute__((ext_vector_type(4)));
typedef unsigned int u32x2 __attribute__((ext_vector_type(2)));
typedef unsigned short u16;
typedef unsigned short u16x4 __attribute__((ext_vector_type(4)));
typedef unsigned short u16x8 __attribute__((ext_vector_type(8)));

#define DEV static __device__ __forceinline__
#define AS1 __attribute__((address_space(1)))
#define AS3 __attribute__((address_space(3)))

DEV u16 f2bf(float f){
  unsigned u = __float_as_uint(f);
  u += 0x7FFFu + ((u >> 16) & 1u);   // round-to-nearest-even
  return (u16)(u >> 16);
}
DEV float bf2f(u16 h){ return __uint_as_float(((u32)h) << 16); }

// async global->LDS, 16B per lane; ldst must be wave-uniform (linear dest).
DEV void stage16(const u16* gsrc, const u16* ldst){
  __builtin_amdgcn_global_load_lds((const AS1 u32*)(unsigned long long)gsrc,
                                   (AS3 u32*)(u32)(unsigned long long)ldst,
                                   16, 0, 0);
}

constexpr int BATCH = 4, LQ = 4096, SK = 4096, DH = 256, BL = BATCH * LQ;
constexpr int NQUART = 4;                 // KV split for occupancy
constexpr int ITERS = SK / NQUART / 64;   // 16 KV-tiles of 64 per block

// ---------------------------------------------------------------------------
// Weight transpose + f32->bf16 cast: src[R][C] -> dst[C][R]
// ---------------------------------------------------------------------------
__global__ void transpose_cvt(const float* __restrict__ src, u16* __restrict__ dst,
                              int R, int C){
  int idx = blockIdx.x * 256 + threadIdx.x;
  if (idx >= R * C) return;
  int r = idx / C, c = idx - r * C;
  dst[(size_t)c * R + r] = f2bf(src[idx]);
}

// source f32 [BL,256] -> hcat bf16 [BL,512] left half
__global__ void cvt_src(const float* __restrict__ src, u16* __restrict__ hcat){
  int idx = blockIdx.x * 256 + threadIdx.x;   // BL*32 total, 8 elems each
  int row = idx >> 5, c = (idx & 31) * 8;
  const float* p = src + (size_t)row * DH + c;
  f32x4 a = *(const f32x4*)p;
  f32x4 b = *(const f32x4*)(p + 4);
  u16x8 h;
  h[0]=f2bf(a[0]); h[1]=f2bf(a[1]); h[2]=f2bf(a[2]); h[3]=f2bf(a[3]);
  h[4]=f2bf(b[0]); h[5]=f2bf(b[1]); h[6]=f2bf(b[2]); h[7]=f2bf(b[3]);
  *(u16x8*)&hcat[(size_t)row * 512 + c] = h;
}

// ---------------------------------------------------------------------------
// GEMM: A[M,K] (f32 or bf16) @ W (given as WT bf16 [N,K]) -> out, BM=BN=128 BK=64
// EPI: 0 = bf16 out, (acc+bias)*scale   (q / k)
//      1 = bf16 out transposed to [B,DH,SK] (v^T), +bias
//      2 = f32 out, +bias (nullable)
//      3 = bf16 out, exact GELU, no bias
// ---------------------------------------------------------------------------
template<bool A_F32, int EPI>
__global__ __launch_bounds__(256, 2) void gemm128(
  const void* __restrict__ Ap, const u16* __restrict__ BTp,
  const float* __restrict__ bias, void* __restrict__ outp,
  int M, int N, int K, float scale)
{
  __shared__ u16 A_lds[128 * 64];
  __shared__ u16 B_lds[128 * 64];
  const int tid = threadIdx.x, lane = tid & 63, wid = tid >> 6;
  const int ql = lane & 31, g = lane >> 5;
  const int m0 = blockIdx.y * 128, n0 = blockIdx.x * 128;
  const int mr = (wid & 1) * 64, nr = (wid >> 1) * 64;

  f32x16 acc[2][2] = {};
  f32x4 afreg[8];
  u32x4 abreg[4];
  u32x4 breg[4];
  const float* Af = (const float*)Ap;
  const u16*   Ab = (const u16*)Ap;

#define G_LOAD_A(kb) do { \
    if constexpr (A_F32) { \
      _Pragma("unroll") \
      for (int i = 0; i < 8; i++){ int item = tid + i*256; int r = item>>4, c = (item&15)*4; \
        afreg[i] = *(const f32x4*)&Af[(size_t)(m0+r)*K + (kb)*64 + c]; } \
    } else { \
      _Pragma("unroll") \
      for (int i = 0; i < 4; i++){ int item = tid + i*256; int r = item>>3, c = (item&7)*8; \
        abreg[i] = *(const u32x4*)&Ab[(size_t)(m0+r)*K + (kb)*64 + c]; } \
    } \
  } while(0)
#define G_LOAD_B(kb) do { \
    _Pragma("unroll") \
    for (int i = 0; i < 4; i++){ int item = tid + i*256; int r = item>>3, c = (item&7)*8; \
      breg[i] = *(const u32x4*)&BTp[(size_t)(n0+r)*K + (kb)*64 + c]; } \
  } while(0)

  G_LOAD_A(0); G_LOAD_B(0);

  const int nkb = K >> 6;
  for (int kb = 0; kb < nkb; ++kb){
    __syncthreads();
    if constexpr (A_F32){
      #pragma unroll
      for (int i = 0; i < 8; i++){ int item = tid + i*256; int r = item>>4, c = (item&15)*4;
        u16x4 h; h[0]=f2bf(afreg[i][0]); h[1]=f2bf(afreg[i][1]);
                 h[2]=f2bf(afreg[i][2]); h[3]=f2bf(afreg[i][3]);
        *(u16x4*)&A_lds[r*64 + (c ^ ((r&7)*8))] = h; }
    } else {
      #pragma unroll
      for (int i = 0; i < 4; i++){ int item = tid + i*256; int r = item>>3, c = (item&7)*8;
        *(u32x4*)&A_lds[r*64 + (c ^ ((r&7)*8))] = abreg[i]; }
    }
    #pragma unroll
    for (int i = 0; i < 4; i++){ int item = tid + i*256; int r = item>>3, c = (item&7)*8;
      *(u32x4*)&B_lds[r*64 + (c ^ ((r&7)*8))] = breg[i]; }
    __syncthreads();
    if (kb + 1 < nkb){ G_LOAD_A(kb+1); G_LOAD_B(kb+1); }

    #pragma unroll
    for (int kk = 0; kk < 4; kk++){
      bf16x8 af[2], bf[2];
      #pragma unroll
      for (int mi = 0; mi < 2; mi++)
        af[mi] = __builtin_bit_cast(bf16x8,
          *(const u32x4*)&A_lds[(mr+mi*32+ql)*64 + ((kk*16+g*8) ^ ((ql&7)*8))]);
      #pragma unroll
      for (int ni = 0; ni < 2; ni++)
        bf[ni] = __builtin_bit_cast(bf16x8,
          *(const u32x4*)&B_lds[(nr+ni*32+ql)*64 + ((kk*16+g*8) ^ ((ql&7)*8))]);
      #pragma unroll
      for (int mi = 0; mi < 2; mi++)
        #pragma unroll
        for (int ni = 0; ni < 2; ni++)
          acc[mi][ni] = __builtin_amdgcn_mfma_f32_32x32x16_bf16(af[mi], bf[ni], acc[mi][ni], 0, 0, 0);
    }
  }

  #pragma unroll
  for (int mi = 0; mi < 2; mi++){
    #pragma unroll
    for (int ni = 0; ni < 2; ni++){
      const int col = n0 + nr + ni*32 + ql;
      const float bv = bias ? bias[col] : 0.f;
      if constexpr (EPI == 1){
        #pragma unroll
        for (int qd = 0; qd < 4; qd++){
          u16x4 h;
          #pragma unroll
          for (int i = 0; i < 4; i++) h[i] = f2bf(acc[mi][ni][qd*4+i] + bv);
          int row0 = m0 + mr + mi*32 + qd*8 + 4*g;
          int bb = row0 >> 12, ss = row0 & 4095;
          *(u16x4*)&((u16*)outp)[((size_t)bb*DH + col)*SK + ss] = h;
        }
      } else {
        #pragma unroll
        for (int j = 0; j < 16; j++){
          int row = m0 + mr + mi*32 + (j&3) + 8*(j>>2) + 4*g;
          float v = acc[mi][ni][j] + bv;
          if constexpr (EPI == 0){
            ((u16*)outp)[(size_t)row*N + col] = f2bf(v * scale);
          } else if constexpr (EPI == 2){
            ((float*)outp)[(size_t)row*N + col] = v;
          } else {
            v = 0.5f * v * (1.f + erff(v * 0.70710678118f));
            ((u16*)outp)[(size_t)row*N + col] = f2bf(v);
          }
        }
      }
    }
  }
}

// ---------------------------------------------------------------------------
// Flash attention. grid (LQ/128, BATCH, NQUART), 256 threads (4 waves).
// Wave owns 32 q-rows. Swapped QK^T: scores^T = mfma(K, Q) -> lane owns
// q-col = lane&31. P stays in register (cvt_pk + permlane32_swap -> PV B-frag).
// Staging via global_load_lds with PRE-SWIZZLED global source (rule 21):
//   K_lds  [s][slot16 ^ (s&31)]   (32-slot XOR, row = 512B)
//   VT_lds [d][slot16 ^ (d&7)]    (8-slot XOR,  row = 128B)
// Two-phase overlap: stage V(it) hides under QK^T, stage K(it+1) under PV.
// q pre-scaled by log2(e)/sqrt(D); softmax in exp2 domain; defer-max (THR=8).
// LDS = 64 KB; target VGPR <= 256 -> 2 blocks/CU co-resident.
// ---------------------------------------------------------------------------
__global__ __launch_bounds__(256, 1) void attn_kernel(
  const u16* __restrict__ qb, const u16* __restrict__ kb,
  const u16* __restrict__ vtb, u16* __restrict__ opart, float* __restrict__ stats)
{
  __shared__ u16 K_lds[64 * 256];    // 32 KB
  __shared__ u16 VT_lds[256 * 64];   // 32 KB

  const int tid = threadIdx.x;
  const int wid = tid >> 6, lane = tid & 63;
  const int ql = lane & 31, g = lane >> 5;
  const int b = blockIdx.y, quart = blockIdx.z;
  const int qrow0 = blockIdx.x * 128 + wid * 32;
  const int s0base = quart * (SK / NQUART);

  const u16* kbase = kb  + (size_t)b * SK * DH;
  const u16* vbase = vtb + (size_t)b * DH * SK;

  // K tile stage: 8 chunks x 1KB/wave; lds linear hw = grp*8 = s*256 + slot*8
#define STAGE_K(s0) do { \
    _Pragma("unroll") \
    for (int i = 0; i < 8; i++){ \
      int grp = tid + i*256; int s = grp>>5, slot = grp&31; \
      stage16(kbase + (size_t)((s0)+s)*DH + ((slot ^ (s&31))<<3), \
              &K_lds[(i*256 + wid*64)*8]); \
    } } while(0)
  // V tile stage: lds linear hw = grp*8 = d*64 + slot*8
#define STAGE_V(s0) do { \
    _Pragma("unroll") \
    for (int i = 0; i < 8; i++){ \
      int grp = tid + i*256; int d = grp>>3, slot = grp&7; \
      stage16(vbase + (size_t)d*SK + (s0) + ((slot ^ (d&7))<<3), \
              &VT_lds[(i*256 + wid*64)*8]); \
    } } while(0)

  STAGE_K(s0base);

  bf16x8 qf[16];
  {
    const u16* qp = qb + ((size_t)(b*LQ + qrow0 + ql)) * DH + g * 8;
    #pragma unroll
    for (int kk = 0; kk < 16; kk++)
      qf[kk] = __builtin_bit_cast(bf16x8, *(const u32x4*)(qp + kk*16));
  }

  f32x16 accO[8] = {};
  float m_run = -1e30f, l_run = 0.f;

  __syncthreads();   // drains K(0)

  for (int it = 0; it < ITERS; ++it){
    const int s0 = s0base + it*64;
    STAGE_V(s0);     // hides under QK^T; drained at mid-barrier

    // QK^T (swapped): ps[st] holds scores for q=lane&31, s=st*32+(j&3)+8*(j>>2)+4g
    f32x16 ps[2];
    __builtin_amdgcn_s_setprio(1);
    #pragma unroll
    for (int st = 0; st < 2; ++st){
      f32x16 a = {};
      #pragma unroll
      for (int kk = 0; kk < 16; ++kk){
        bf16x8 kf = __builtin_bit_cast(bf16x8,
          *(const u32x4*)&K_lds[(st*32+ql)*256 + (((kk*2+g) ^ ql)<<3)]);
        a = __builtin_amdgcn_mfma_f32_32x32x16_bf16(kf, qf[kk], a, 0, 0, 0);
      }
      ps[st] = a;
    }
    __builtin_amdgcn_s_setprio(0);

    __syncthreads();                       // V(it) staged; K free
    if (it + 1 < ITERS) STAGE_K(s0 + 64);  // hides under softmax+PV

    // online softmax (exp2 domain) with defer-max
    float vmax = -1e30f;
    #pragma unroll
    for (int st = 0; st < 2; st++)
      #pragma unroll
      for (int j = 0; j < 16; j++) vmax = fmaxf(vmax, ps[st][j]);
    vmax = fmaxf(vmax, __shfl_xor(vmax, 32, 64));
    if (!__all(vmax <= m_run + 8.0f)){
      float m_new = fmaxf(m_run, vmax);
      float alpha = exp2f(m_run - m_new);
      l_run *= alpha;
      #pragma unroll
      for (int dt = 0; dt < 8; dt++)
        #pragma unroll
        for (int j = 0; j < 16; j++) accO[dt][j] *= alpha;
      m_run = m_new;
    }
    float psum = 0.f;
    #pragma unroll
    for (int st = 0; st < 2; st++)
      #pragma unroll
      for (int j = 0; j < 16; j++){ float p = exp2f(ps[st][j] - m_run); ps[st][j] = p; psum += p; }
    psum += __shfl_xor(psum, 32, 64);
    l_run += psum;

    // in-register P -> PV B-fragments (cvt_pk + permlane32_swap)
    u32 Wp[2][4][2];
    #pragma unroll
    for (int st = 0; st < 2; st++)
      #pragma unroll
      for (int qd = 0; qd < 4; qd++)
        #pragma unroll
        for (int h = 0; h < 2; h++){
          float lo = ps[st][qd*4 + 2*h], hi = ps[st][qd*4 + 2*h + 1];
          asm("v_cvt_pk_bf16_f32 %0, %1, %2" : "=v"(Wp[st][qd][h]) : "v"(lo), "v"(hi));
        }
    bf16x8 pf[4];
    #pragma unroll
    for (int ks = 0; ks < 4; ks++){
      const int st = ks >> 1, qp2 = (ks & 1) * 2;
      u32 a0 = Wp[st][qp2][0], b0 = Wp[st][qp2+1][0];
      u32 a1 = Wp[st][qp2][1], b1 = Wp[st][qp2+1][1];
      asm("v_permlane32_swap_b32 %0, %1" : "+v"(a0), "+v"(b0));
      asm("v_permlane32_swap_b32 %0, %1" : "+v"(a1), "+v"(b1));
      u32x4 w; w[0] = a0; w[1] = a1; w[2] = b0; w[3] = b1;
      pf[ks] = __builtin_bit_cast(bf16x8, w);
    }

    // PV: O^T += mfma(VT, P)
    __builtin_amdgcn_s_setprio(1);
    #pragma unroll
    for (int dt = 0; dt < 8; dt++){
      #pragma unroll
      for (int ks = 0; ks < 4; ks++){
        bf16x8 vf = __builtin_bit_cast(bf16x8,
          *(const u32x4*)&VT_lds[(dt*32+ql)*64 + (((ks*2+g) ^ (ql&7))<<3)]);
        accO[dt] = __builtin_amdgcn_mfma_f32_32x32x16_bf16(vf, pf[ks], accO[dt], 0, 0, 0);
      }
    }
    __builtin_amdgcn_s_setprio(0);

    __syncthreads();   // K(it+1) staged; VT free
  }

  const int rowb = b * LQ + qrow0;
  if (g == 0){
    stats[(size_t)(quart*2 + 0)*BL + rowb + ql] = m_run;
    stats[(size_t)(quart*2 + 1)*BL + rowb + ql] = l_run;
  }

  // transpose O^T -> row-major via LDS scratch aliased onto K_lds; bf16 store
  float* scratch = (float*)&K_lds[wid * 2112];   // 32x33 f32 per wave
  #pragma unroll
  for (int dt = 0; dt < 8; dt++){
    #pragma unroll
    for (int j = 0; j < 16; j++){
      int dl = (j&3) + 8*(j>>2) + 4*g;
      scratch[ql*33 + dl] = accO[dt][j];
    }
    int q2 = lane >> 1, dl2 = (lane & 1) * 16;
    u16x8 h0, h1;
    #pragma unroll
    for (int i = 0; i < 8; i++){ h0[i] = f2bf(scratch[q2*33 + dl2 + i]);
                                 h1[i] = f2bf(scratch[q2*33 + dl2 + 8 + i]); }
    u16* op = &opart[((size_t)quart*BL + rowb + q2)*DH + dt*32 + dl2];
    *(u16x8*)op = h0;
    *(u16x8*)(op + 8) = h1;
  }
}

// combine the four KV-quarter partials -> message bf16
__global__ void merge_kernel(const u16* __restrict__ opart,
                             const float* __restrict__ stats, u16* __restrict__ msg){
  int gid = blockIdx.x * 256 + threadIdx.x;   // BL*32
  int row = gid >> 5, d0 = (gid & 31) * 8;
  float m[4], l[4];
  #pragma unroll
  for (int q = 0; q < 4; q++){
    m[q] = stats[(size_t)(q*2 + 0)*BL + row];
    l[q] = stats[(size_t)(q*2 + 1)*BL + row];
  }
  float mm = fmaxf(fmaxf(m[0], m[1]), fmaxf(m[2], m[3]));
  float w[4], denom = 0.f;
  #pragma unroll
  for (int q = 0; q < 4; q++){ w[q] = exp2f(m[q] - mm); denom += l[q]*w[q]; }
  float inv = 1.f / denom;
  float acc[8] = {};
  #pragma unroll
  for (int q = 0; q < 4; q++){
    u16x8 o = *(const u16x8*)&opart[((size_t)q*BL + row)*DH + d0];
    #pragma unroll
    for (int i = 0; i < 8; i++) acc[i] += bf2f(o[i]) * w[q];
  }
  u16x8 h;
  #pragma unroll
  for (int i = 0; i < 8; i++) h[i] = f2bf(acc[i] * inv);
  *(u16x8*)&msg[(size_t)row*DH + d0] = h;
}

// LayerNorm over D=256. OMODE 0: bf16 -> hcat[:,256:512]. OMODE 1: f32 out = src + LN(x).
template<int OMODE>
__global__ void ln_kernel(const float* __restrict__ x, const float* __restrict__ gamma,
                          const float* __restrict__ beta, const float* __restrict__ src,
                          void* __restrict__ outp){
  int wid = threadIdx.x >> 6, lane = threadIdx.x & 63;
  int row = blockIdx.x * 4 + wid;
  const float* xr = x + (size_t)row * DH;
  f32x4 v = *(const f32x4*)&xr[lane*4];
  float s1 = v[0]+v[1]+v[2]+v[3];
  float s2 = v[0]*v[0]+v[1]*v[1]+v[2]*v[2]+v[3]*v[3];
  #pragma unroll
  for (int m = 1; m < 64; m <<= 1){ s1 += __shfl_xor(s1, m, 64); s2 += __shfl_xor(s2, m, 64); }
  float mu = s1 * (1.f/DH);
  float var = s2 * (1.f/DH) - mu*mu;
  float rstd = rsqrtf(var + 1e-5f);
  f32x4 gv = *(const f32x4*)&gamma[lane*4];
  f32x4 bv = *(const f32x4*)&beta[lane*4];
  if constexpr (OMODE == 0){
    u16x4 h;
    #pragma unroll
    for (int i = 0; i < 4; i++) h[i] = f2bf((v[i]-mu)*rstd*gv[i] + bv[i]);
    *(u16x4*)&((u16*)outp)[(size_t)row*512 + 256 + lane*4] = h;
  } else {
    const float* sr = src + (size_t)row * DH;
    f32x4 s = *(const f32x4*)&sr[lane*4];
    f32x4 o;
    #pragma unroll
    for (int i = 0; i < 4; i++) o[i] = s[i] + (v[i]-mu)*rstd*gv[i] + bv[i];
    *(f32x4*)&((float*)outp)[(size_t)row*DH + lane*4] = o;
  }
}

// ---------------------------------------------------------------------------
extern "C" void kernel_launch(void* const* d_in, const int* in_sizes, int n_in,
                              void* d_out, int out_size, void* d_ws, size_t ws_size,
                              hipStream_t stream)
{
  const float* source = (const float*)d_in[0];
  const float* target = (const float*)d_in[1];
  const float* Wq = (const float*)d_in[2];  const float* bq = (const float*)d_in[3];
  const float* Wk = (const float*)d_in[4];  const float* bk = (const float*)d_in[5];
  const float* Wv = (const float*)d_in[6];  const float* bv = (const float*)d_in[7];
  const float* Wm = (const float*)d_in[8];  const float* bm = (const float*)d_in[9];
  const float* g1 = (const float*)d_in[10]; const float* be1 = (const float*)d_in[11];
  const float* W1 = (const float*)d_in[12]; const float* W2 = (const float*)d_in[13];
  const float* g2 = (const float*)d_in[14]; const float* be2 = (const float*)d_in[15];

  char* ws = (char*)d_ws;
  u16* WqT = (u16*)(ws);
  u16* WkT = (u16*)(ws + (size_t)(1u<<17));
  u16* WvT = (u16*)(ws + (size_t)2*(1u<<17));
  u16* WmT = (u16*)(ws + (size_t)3*(1u<<17));
  u16* W1T = (u16*)(ws + (size_t)4*(1u<<17));
  u16* W2T = (u16*)(ws + (size_t)4*(1u<<17) + (1u<<19));
  size_t off = (size_t)4*(1u<<17) + (1u<<19) + (1u<<18);   // 1,310,720
  u16* qbuf  = (u16*)(ws + off); off += (size_t)BL*DH*2;
  u16* kbuf  = (u16*)(ws + off); off += (size_t)BL*DH*2;
  u16* vtbuf = (u16*)(ws + off); off += (size_t)BL*DH*2;
  u16* msg   = (u16*)(ws + off); off += (size_t)BL*DH*2;
  u16* hcat  = (u16*)(ws + off); off += (size_t)BL*512*2;
  u16* hact  = (u16*)(ws + off); off += (size_t)BL*512*2;
  u16* opart = (u16*)(ws + off); off += (size_t)NQUART*BL*DH*2;  // bf16 partials
  float* stats = (float*)(ws + off); off += (size_t)2*NQUART*BL*4;
  float* msg2 = (float*)opart;  // alias: opart dead after merge
  float* h2   = (float*)qbuf;   // alias: q/k dead after attention (spans qbuf+kbuf)

  // prep: weight transposes (bf16) + source -> hcat left half
  transpose_cvt<<<dim3(256), 256, 0, stream>>>(Wq, WqT, 256, 256);
  transpose_cvt<<<dim3(256), 256, 0, stream>>>(Wk, WkT, 256, 256);
  transpose_cvt<<<dim3(256), 256, 0, stream>>>(Wv, WvT, 256, 256);
  transpose_cvt<<<dim3(256), 256, 0, stream>>>(Wm, WmT, 256, 256);
  transpose_cvt<<<dim3(1024), 256, 0, stream>>>(W1, W1T, 512, 512);
  transpose_cvt<<<dim3(512), 256, 0, stream>>>(W2, W2T, 512, 256);
  cvt_src<<<dim3(BL*32/256), 256, 0, stream>>>(source, hcat);

  // projections (q pre-scaled by log2(e)/sqrt(D) for exp2-domain softmax)
  const float qscale = 1.4426950408889634f / 16.0f;
  gemm128<true, 0><<<dim3(2, BL/128), 256, 0, stream>>>(source, WqT, bq, qbuf, BL, 256, 256, qscale);
  gemm128<true, 0><<<dim3(2, BL/128), 256, 0, stream>>>(target, WkT, bk, kbuf, BL, 256, 256, 1.0f);
  gemm128<true, 1><<<dim3(2, BL/128), 256, 0, stream>>>(target, WvT, bv, vtbuf, BL, 256, 256, 1.0f);

  // flash attention (4 KV quarters) + merge
  attn_kernel<<<dim3(LQ/128, BATCH, NQUART), 256, 0, stream>>>(qbuf, kbuf, vtbuf, opart, stats);
  merge_kernel<<<dim3(BL*32/256), 256, 0, stream>>>(opart, stats, msg);

  // output proj + LN1 -> hcat right half
  gemm128<false, 2><<<dim3(2, BL/128), 256, 0, stream>>>(msg, WmT, bm, msg2, BL, 256, 256, 1.0f);
  ln_kernel<0><<<dim3(BL/4), 256, 0, stream>>>(msg2, g1, be1, nullptr, hcat);

  // MLP: GELU(hcat @ W1) @ W2, LN2 + residual
  gemm128<false, 3><<<dim3(4, BL/128), 256, 0, stream>>>(hcat, W1T, nullptr, hact, BL, 512, 512, 1.0f);
  gemm128<false, 2><<<dim3(2, BL/128), 256, 0, stream>>>(hact, W2T, nullptr, h2, BL, 256, 512, 1.0f);
  ln_kernel<1><<<dim3(BL/4), 256, 0, stream>>>(h2, g2, be2, source, d_out);
}

// Round 4
// 209.701 us; speedup vs baseline: 2.0106x; 1.1193x over previous
//
#include <hip/hip_runtime.h>

typedef __bf16 bf16x8 __attribute__((ext_vector_type(8)));
typedef float f32x16 __attribute__((ext_vector_type(16)));
typedef float f32x4 __attribute__((ext_vector_type(4)));
typedef unsigned int u32;
typedef unsigned int u32x4 __attribute__((ext_vector_type(4)));
typedef unsigned short u16;
typedef unsigned short u16x4 __attribute__((ext_vector_type(4)));
typedef unsigned short u16x8 __attribute__((ext_vector_type(8)));

#define DEV static __device__ __forceinline__
#define AS1 __attribute__((address_space(1)))
#define AS3 __attribute__((address_space(3)))

DEV u16 f2bf(float f){
  unsigned u = __float_as_uint(f);
  u += 0x7FFFu + ((u >> 16) & 1u);   // round-to-nearest-even
  return (u16)(u >> 16);
}
DEV float bf2f(u16 h){ return __uint_as_float(((u32)h) << 16); }

// async global->LDS, 16B per lane; ldst must be wave-uniform (linear dest).
DEV void stage16(const u16* gsrc, const u16* ldst){
  __builtin_amdgcn_global_load_lds((const AS1 u32*)(unsigned long long)gsrc,
                                   (AS3 u32*)(u32)(unsigned long long)ldst,
                                   16, 0, 0);
}

constexpr int BATCH = 4, LQ = 4096, SK = 4096, DH = 256, BL = BATCH * LQ;
constexpr int NHALF = 2;                  // KV split
constexpr int ITERS = SK / NHALF / 64;    // 32 KV-tiles of 64 per block

// ---------------------------------------------------------------------------
// All six weight transposes (f32 [R][C] -> bf16 [C][R]) in one launch.
// ---------------------------------------------------------------------------
__global__ void prep_weights(const float* __restrict__ Wq, const float* __restrict__ Wk,
                             const float* __restrict__ Wv, const float* __restrict__ Wm,
                             const float* __restrict__ W1, const float* __restrict__ W2,
                             u16* __restrict__ WqT, u16* __restrict__ WkT,
                             u16* __restrict__ WvT, u16* __restrict__ WmT,
                             u16* __restrict__ W1T, u16* __restrict__ W2T){
  int idx = blockIdx.x * 256 + threadIdx.x;
  if (idx < 262144){                       // four 256x256
    int which = idx >> 16, i2 = idx & 65535;
    int r = i2 >> 8, c = i2 & 255;
    const float* S = (which==0)?Wq:(which==1)?Wk:(which==2)?Wv:Wm;
    u16*         D = (which==0)?WqT:(which==1)?WkT:(which==2)?WvT:WmT;
    D[c*256 + r] = f2bf(S[i2]);
  } else if (idx < 524288){                // W1 512x512
    int i2 = idx - 262144;
    int r = i2 >> 9, c = i2 & 511;
    W1T[c*512 + r] = f2bf(W1[i2]);
  } else {                                 // W2 512x256
    int i2 = idx - 524288;
    int r = i2 >> 8, c = i2 & 255;
    W2T[(size_t)c*512 + r] = f2bf(W2[i2]);
  }
}

// source f32 -> hcat[:,0:256] (bf16, row stride 512); target f32 -> tgtb bf16
__global__ void cvt_inputs(const float* __restrict__ src, const float* __restrict__ tgt,
                           u16* __restrict__ hcat, u16* __restrict__ tgtb){
  int idx = blockIdx.x * 256 + threadIdx.x;   // 2 * BL*32, 8 elems each
  const bool isT = idx >= BL*32;
  if (isT) idx -= BL*32;
  int row = idx >> 5, c = (idx & 31) * 8;
  const float* p = (isT ? tgt : src) + (size_t)row * DH + c;
  f32x4 a = *(const f32x4*)p;
  f32x4 b = *(const f32x4*)(p + 4);
  u16x8 h;
  h[0]=f2bf(a[0]); h[1]=f2bf(a[1]); h[2]=f2bf(a[2]); h[3]=f2bf(a[3]);
  h[4]=f2bf(b[0]); h[5]=f2bf(b[1]); h[6]=f2bf(b[2]); h[7]=f2bf(b[3]);
  if (isT) *(u16x8*)&tgtb[(size_t)row * DH + c] = h;
  else     *(u16x8*)&hcat[(size_t)row * 512 + c] = h;
}

// ---------------------------------------------------------------------------
// GEMM: A bf16 [M,K] (row stride lda) @ W (WT bf16 [N,K]) -> out, BM=BN=128 BK=64
// EPI: 0 = bf16 out, (acc+bias)*scale   (q / k)
//      1 = bf16 out transposed to [B,DH,SK] (v^T), +bias
//      2 = f32 out, +bias (nullable)
//      3 = bf16 out, exact GELU, no bias
// ---------------------------------------------------------------------------
template<int EPI>
__global__ __launch_bounds__(256, 2) void gemm128(
  const u16* __restrict__ Ab, int lda, const u16* __restrict__ BTp,
  const float* __restrict__ bias, void* __restrict__ outp,
  int M, int N, int K, float scale)
{
  __shared__ u16 A_lds[128 * 64];
  __shared__ u16 B_lds[128 * 64];
  const int tid = threadIdx.x, lane = tid & 63, wid = tid >> 6;
  const int ql = lane & 31, g = lane >> 5;
  const int m0 = blockIdx.y * 128, n0 = blockIdx.x * 128;
  const int mr = (wid & 1) * 64, nr = (wid >> 1) * 64;

  f32x16 acc[2][2] = {};
  u32x4 abreg[4];
  u32x4 breg[4];

#define G_LOAD_A(kb) do { \
    _Pragma("unroll") \
    for (int i = 0; i < 4; i++){ int item = tid + i*256; int r = item>>3, c = (item&7)*8; \
      abreg[i] = *(const u32x4*)&Ab[(size_t)(m0+r)*lda + (kb)*64 + c]; } \
  } while(0)
#define G_LOAD_B(kb) do { \
    _Pragma("unroll") \
    for (int i = 0; i < 4; i++){ int item = tid + i*256; int r = item>>3, c = (item&7)*8; \
      breg[i] = *(const u32x4*)&BTp[(size_t)(n0+r)*K + (kb)*64 + c]; } \
  } while(0)

  G_LOAD_A(0); G_LOAD_B(0);

  const int nkb = K >> 6;
  for (int kb = 0; kb < nkb; ++kb){
    __syncthreads();
    #pragma unroll
    for (int i = 0; i < 4; i++){ int item = tid + i*256; int r = item>>3, c = (item&7)*8;
      *(u32x4*)&A_lds[r*64 + (c ^ ((r&7)*8))] = abreg[i]; }
    #pragma unroll
    for (int i = 0; i < 4; i++){ int item = tid + i*256; int r = item>>3, c = (item&7)*8;
      *(u32x4*)&B_lds[r*64 + (c ^ ((r&7)*8))] = breg[i]; }
    __syncthreads();
    if (kb + 1 < nkb){ G_LOAD_A(kb+1); G_LOAD_B(kb+1); }

    #pragma unroll
    for (int kk = 0; kk < 4; kk++){
      bf16x8 af[2], bf[2];
      #pragma unroll
      for (int mi = 0; mi < 2; mi++)
        af[mi] = __builtin_bit_cast(bf16x8,
          *(const u32x4*)&A_lds[(mr+mi*32+ql)*64 + ((kk*16+g*8) ^ ((ql&7)*8))]);
      #pragma unroll
      for (int ni = 0; ni < 2; ni++)
        bf[ni] = __builtin_bit_cast(bf16x8,
          *(const u32x4*)&B_lds[(nr+ni*32+ql)*64 + ((kk*16+g*8) ^ ((ql&7)*8))]);
      #pragma unroll
      for (int mi = 0; mi < 2; mi++)
        #pragma unroll
        for (int ni = 0; ni < 2; ni++)
          acc[mi][ni] = __builtin_amdgcn_mfma_f32_32x32x16_bf16(af[mi], bf[ni], acc[mi][ni], 0, 0, 0);
    }
  }

  #pragma unroll
  for (int mi = 0; mi < 2; mi++){
    #pragma unroll
    for (int ni = 0; ni < 2; ni++){
      const int col = n0 + nr + ni*32 + ql;
      const float bv = bias ? bias[col] : 0.f;
      if constexpr (EPI == 1){
        #pragma unroll
        for (int qd = 0; qd < 4; qd++){
          u16x4 h;
          #pragma unroll
          for (int i = 0; i < 4; i++) h[i] = f2bf(acc[mi][ni][qd*4+i] + bv);
          int row0 = m0 + mr + mi*32 + qd*8 + 4*g;
          int bb = row0 >> 12, ss = row0 & 4095;
          *(u16x4*)&((u16*)outp)[((size_t)bb*DH + col)*SK + ss] = h;
        }
      } else {
        #pragma unroll
        for (int j = 0; j < 16; j++){
          int row = m0 + mr + mi*32 + (j&3) + 8*(j>>2) + 4*g;
          float v = acc[mi][ni][j] + bv;
          if constexpr (EPI == 0){
            ((u16*)outp)[(size_t)row*N + col] = f2bf(v * scale);
          } else if constexpr (EPI == 2){
            ((float*)outp)[(size_t)row*N + col] = v;
          } else {
            v = 0.5f * v * (1.f + erff(v * 0.70710678118f));
            ((u16*)outp)[(size_t)row*N + col] = f2bf(v);
          }
        }
      }
    }
  }
}

// ---------------------------------------------------------------------------
// Flash attention. grid (LQ/128, BATCH, NHALF), 256 threads (4 waves).
// Wave owns 32 q-rows. Swapped QK^T: scores^T = mfma(K, Q) -> lane owns
// q-col = lane&31. P in register (cvt_pk + permlane32_swap -> PV B-frag).
// DOUBLE-BUFFERED K/V LDS (128 KB): stage tile it+1 right after the single
// per-iter barrier -> a full iteration of compute covers the staging latency,
// so the vmcnt(0) drain at the barrier is ~free.
// Staging via global_load_lds with PRE-SWIZZLED global source (rule 21):
//   K_lds  [s][slot16 ^ (s&31)]   (32-slot XOR, row = 512B)
//   VT_lds [d][slot16 ^ (d&7)]    (8-slot XOR,  row = 128B)
// q pre-scaled by log2(e)/sqrt(D); softmax in exp2 domain; defer-max (THR=8).
// ---------------------------------------------------------------------------
__global__ __launch_bounds__(256, 1) void attn_kernel(
  const u16* __restrict__ qb, const u16* __restrict__ kb,
  const u16* __restrict__ vtb, u16* __restrict__ opart, float* __restrict__ stats)
{
  __shared__ u16 K_lds[2][64 * 256];    // 2 x 32 KB
  __shared__ u16 VT_lds[2][256 * 64];   // 2 x 32 KB

  const int tid = threadIdx.x;
  const int wid = tid >> 6, lane = tid & 63;
  const int ql = lane & 31, g = lane >> 5;
  const int b = blockIdx.y, half = blockIdx.z;
  const int qrow0 = blockIdx.x * 128 + wid * 32;
  const int s0base = half * (SK / NHALF);

  const u16* kbase = kb  + (size_t)b * SK * DH;
  const u16* vbase = vtb + (size_t)b * DH * SK;

  // K tile stage: 8 chunks x 1KB/wave; lds linear hw = grp*8 = s*256 + slot*8
#define STAGE_K(bi, s0) do { \
    _Pragma("unroll") \
    for (int i = 0; i < 8; i++){ \
      int grp = tid + i*256; int s = grp>>5, slot = grp&31; \
      stage16(kbase + (size_t)((s0)+s)*DH + ((slot ^ (s&31))<<3), \
              &K_lds[bi][(i*256 + wid*64)*8]); \
    } } while(0)
  // V tile stage: lds linear hw = grp*8 = d*64 + slot*8
#define STAGE_V(bi, s0) do { \
    _Pragma("unroll") \
    for (int i = 0; i < 8; i++){ \
      int grp = tid + i*256; int d = grp>>3, slot = grp&7; \
      stage16(vbase + (size_t)d*SK + (s0) + ((slot ^ (d&7))<<3), \
              &VT_lds[bi][(i*256 + wid*64)*8]); \
    } } while(0)

  STAGE_K(0, s0base);
  STAGE_V(0, s0base);

  bf16x8 qf[16];
  {
    const u16* qp = qb + ((size_t)(b*LQ + qrow0 + ql)) * DH + g * 8;
    #pragma unroll
    for (int kk = 0; kk < 16; kk++)
      qf[kk] = __builtin_bit_cast(bf16x8, *(const u32x4*)(qp + kk*16));
  }

  f32x16 accO[8] = {};
  float m_run = -1e30f, l_run = 0.f;

  __syncthreads();   // drains tile 0

  for (int it = 0; it < ITERS; ++it){
    const int cur = it & 1;
    if (it + 1 < ITERS){                       // stage next tile into other buf;
      STAGE_K(cur ^ 1, s0base + (it+1)*64);    // covered by this whole iteration
      STAGE_V(cur ^ 1, s0base + (it+1)*64);
    }

    // QK^T (swapped): ps[st] holds scores for q=lane&31, s=st*32+(j&3)+8*(j>>2)+4g
    f32x16 ps[2];
    __builtin_amdgcn_s_setprio(1);
    #pragma unroll
    for (int st = 0; st < 2; ++st){
      f32x16 a = {};
      #pragma unroll
      for (int kk = 0; kk < 16; ++kk){
        bf16x8 kf = __builtin_bit_cast(bf16x8,
          *(const u32x4*)&K_lds[cur][(st*32+ql)*256 + (((kk*2+g) ^ ql)<<3)]);
        a = __builtin_amdgcn_mfma_f32_32x32x16_bf16(kf, qf[kk], a, 0, 0, 0);
      }
      ps[st] = a;
    }
    __builtin_amdgcn_s_setprio(0);

    // online softmax (exp2 domain) with defer-max
    float vmax = -1e30f;
    #pragma unroll
    for (int st = 0; st < 2; st++)
      #pragma unroll
      for (int j = 0; j < 16; j++) vmax = fmaxf(vmax, ps[st][j]);
    vmax = fmaxf(vmax, __shfl_xor(vmax, 32, 64));
    if (!__all(vmax <= m_run + 8.0f)){
      float m_new = fmaxf(m_run, vmax);
      float alpha = exp2f(m_run - m_new);
      l_run *= alpha;
      #pragma unroll
      for (int dt = 0; dt < 8; dt++)
        #pragma unroll
        for (int j = 0; j < 16; j++) accO[dt][j] *= alpha;
      m_run = m_new;
    }
    float psum = 0.f;
    #pragma unroll
    for (int st = 0; st < 2; st++)
      #pragma unroll
      for (int j = 0; j < 16; j++){ float p = exp2f(ps[st][j] - m_run); ps[st][j] = p; psum += p; }
    psum += __shfl_xor(psum, 32, 64);
    l_run += psum;

    // in-register P -> PV B-fragments (cvt_pk + permlane32_swap)
    u32 Wp[2][4][2];
    #pragma unroll
    for (int st = 0; st < 2; st++)
      #pragma unroll
      for (int qd = 0; qd < 4; qd++)
        #pragma unroll
        for (int h = 0; h < 2; h++){
          float lo = ps[st][qd*4 + 2*h], hi = ps[st][qd*4 + 2*h + 1];
          asm("v_cvt_pk_bf16_f32 %0, %1, %2" : "=v"(Wp[st][qd][h]) : "v"(lo), "v"(hi));
        }
    bf16x8 pf[4];
    #pragma unroll
    for (int ks = 0; ks < 4; ks++){
      const int st = ks >> 1, qp2 = (ks & 1) * 2;
      u32 a0 = Wp[st][qp2][0], b0 = Wp[st][qp2+1][0];
      u32 a1 = Wp[st][qp2][1], b1 = Wp[st][qp2+1][1];
      asm("v_permlane32_swap_b32 %0, %1" : "+v"(a0), "+v"(b0));
      asm("v_permlane32_swap_b32 %0, %1" : "+v"(a1), "+v"(b1));
      u32x4 w; w[0] = a0; w[1] = a1; w[2] = b0; w[3] = b1;
      pf[ks] = __builtin_bit_cast(bf16x8, w);
    }

    // PV: O^T += mfma(VT, P)
    __builtin_amdgcn_s_setprio(1);
    #pragma unroll
    for (int dt = 0; dt < 8; dt++){
      #pragma unroll
      for (int ks = 0; ks < 4; ks++){
        bf16x8 vf = __builtin_bit_cast(bf16x8,
          *(const u32x4*)&VT_lds[cur][(dt*32+ql)*64 + (((ks*2+g) ^ (ql&7))<<3)]);
        accO[dt] = __builtin_amdgcn_mfma_f32_32x32x16_bf16(vf, pf[ks], accO[dt], 0, 0, 0);
      }
    }
    __builtin_amdgcn_s_setprio(0);

    __syncthreads();   // compute on buf[cur] done; buf[cur^1] fully staged
  }

  const int rowb = b * LQ + qrow0;
  if (g == 0){
    stats[(size_t)(half*2 + 0)*BL + rowb + ql] = m_run;
    stats[(size_t)(half*2 + 1)*BL + rowb + ql] = l_run;
  }

  // transpose O^T -> row-major via LDS scratch aliased onto K_lds; bf16 store
  float* scratch = (float*)&K_lds[0][wid * 2112];   // 32x33 f32 per wave
  #pragma unroll
  for (int dt = 0; dt < 8; dt++){
    #pragma unroll
    for (int j = 0; j < 16; j++){
      int dl = (j&3) + 8*(j>>2) + 4*g;
      scratch[ql*33 + dl] = accO[dt][j];
    }
    int q2 = lane >> 1, dl2 = (lane & 1) * 16;
    u16x8 h0, h1;
    #pragma unroll
    for (int i = 0; i < 8; i++){ h0[i] = f2bf(scratch[q2*33 + dl2 + i]);
                                 h1[i] = f2bf(scratch[q2*33 + dl2 + 8 + i]); }
    u16* op = &opart[((size_t)half*BL + rowb + q2)*DH + dt*32 + dl2];
    *(u16x8*)op = h0;
    *(u16x8*)(op + 8) = h1;
  }
}

// combine the two KV-half partials -> message bf16
__global__ void merge_kernel(const u16* __restrict__ opart,
                             const float* __restrict__ stats, u16* __restrict__ msg){
  int gid = blockIdx.x * 256 + threadIdx.x;   // BL*32
  int row = gid >> 5, d0 = (gid & 31) * 8;
  float m0 = stats[row],              l0 = stats[(size_t)BL   + row];
  float m1 = stats[(size_t)2*BL+row], l1 = stats[(size_t)3*BL + row];
  float mm = fmaxf(m0, m1);
  float w0 = exp2f(m0 - mm), w1 = exp2f(m1 - mm);
  float inv = 1.f / (l0*w0 + l1*w1);
  u16x8 o0 = *(const u16x8*)&opart[(size_t)row*DH + d0];
  u16x8 o1 = *(const u16x8*)&opart[((size_t)BL + row)*DH + d0];
  u16x8 h;
  #pragma unroll
  for (int i = 0; i < 8; i++) h[i] = f2bf((bf2f(o0[i])*w0 + bf2f(o1[i])*w1) * inv);
  *(u16x8*)&msg[(size_t)row*DH + d0] = h;
}

// LayerNorm over D=256. OMODE 0: bf16 -> hcat[:,256:512]. OMODE 1: f32 out = src + LN(x).
template<int OMODE>
__global__ void ln_kernel(const float* __restrict__ x, const float* __restrict__ gamma,
                          const float* __restrict__ beta, const float* __restrict__ src,
                          void* __restrict__ outp){
  int wid = threadIdx.x >> 6, lane = threadIdx.x & 63;
  int row = blockIdx.x * 4 + wid;
  const float* xr = x + (size_t)row * DH;
  f32x4 v = *(const f32x4*)&xr[lane*4];
  float s1 = v[0]+v[1]+v[2]+v[3];
  float s2 = v[0]*v[0]+v[1]*v[1]+v[2]*v[2]+v[3]*v[3];
  #pragma unroll
  for (int m = 1; m < 64; m <<= 1){ s1 += __shfl_xor(s1, m, 64); s2 += __shfl_xor(s2, m, 64); }
  float mu = s1 * (1.f/DH);
  float var = s2 * (1.f/DH) - mu*mu;
  float rstd = rsqrtf(var + 1e-5f);
  f32x4 gv = *(const f32x4*)&gamma[lane*4];
  f32x4 bv = *(const f32x4*)&beta[lane*4];
  if constexpr (OMODE == 0){
    u16x4 h;
    #pragma unroll
    for (int i = 0; i < 4; i++) h[i] = f2bf((v[i]-mu)*rstd*gv[i] + bv[i]);
    *(u16x4*)&((u16*)outp)[(size_t)row*512 + 256 + lane*4] = h;
  } else {
    const float* sr = src + (size_t)row * DH;
    f32x4 s = *(const f32x4*)&sr[lane*4];
    f32x4 o;
    #pragma unroll
    for (int i = 0; i < 4; i++) o[i] = s[i] + (v[i]-mu)*rstd*gv[i] + bv[i];
    *(f32x4*)&((float*)outp)[(size_t)row*DH + lane*4] = o;
  }
}

// ---------------------------------------------------------------------------
extern "C" void kernel_launch(void* const* d_in, const int* in_sizes, int n_in,
                              void* d_out, int out_size, void* d_ws, size_t ws_size,
                              hipStream_t stream)
{
  const float* source = (const float*)d_in[0];
  const float* target = (const float*)d_in[1];
  const float* Wq = (const float*)d_in[2];  const float* bq = (const float*)d_in[3];
  const float* Wk = (const float*)d_in[4];  const float* bk = (const float*)d_in[5];
  const float* Wv = (const float*)d_in[6];  const float* bv = (const float*)d_in[7];
  const float* Wm = (const float*)d_in[8];  const float* bm = (const float*)d_in[9];
  const float* g1 = (const float*)d_in[10]; const float* be1 = (const float*)d_in[11];
  const float* W1 = (const float*)d_in[12]; const float* W2 = (const float*)d_in[13];
  const float* g2 = (const float*)d_in[14]; const float* be2 = (const float*)d_in[15];

  char* ws = (char*)d_ws;
  u16* WqT = (u16*)(ws);
  u16* WkT = (u16*)(ws + (size_t)(1u<<17));
  u16* WvT = (u16*)(ws + (size_t)2*(1u<<17));
  u16* WmT = (u16*)(ws + (size_t)3*(1u<<17));
  u16* W1T = (u16*)(ws + (size_t)4*(1u<<17));
  u16* W2T = (u16*)(ws + (size_t)4*(1u<<17) + (1u<<19));
  size_t off = (size_t)4*(1u<<17) + (1u<<19) + (1u<<18);   // 1,310,720
  u16* qbuf  = (u16*)(ws + off); off += (size_t)BL*DH*2;
  u16* kbuf  = (u16*)(ws + off); off += (size_t)BL*DH*2;
  u16* vtbuf = (u16*)(ws + off); off += (size_t)BL*DH*2;
  u16* msg   = (u16*)(ws + off); off += (size_t)BL*DH*2;
  u16* tgtb  = (u16*)(ws + off); off += (size_t)BL*DH*2;
  u16* hcat  = (u16*)(ws + off); off += (size_t)BL*512*2;
  u16* hact  = (u16*)(ws + off); off += (size_t)BL*512*2;
  u16* opart = (u16*)(ws + off); off += (size_t)NHALF*BL*DH*2;  // bf16 partials
  float* stats = (float*)(ws + off); off += (size_t)2*NHALF*BL*4;
  float* msg2 = (float*)opart;  // alias: opart dead after merge
  float* h2   = (float*)qbuf;   // alias: q/k dead after attention (spans qbuf+kbuf)

  // prep: weight transposes (bf16) + input casts
  prep_weights<<<dim3(2560), 256, 0, stream>>>(Wq, Wk, Wv, Wm, W1, W2,
                                               WqT, WkT, WvT, WmT, W1T, W2T);
  cvt_inputs<<<dim3(2*BL*32/256), 256, 0, stream>>>(source, target, hcat, tgtb);

  // projections (q pre-scaled by log2(e)/sqrt(D) for exp2-domain softmax)
  const float qscale = 1.4426950408889634f / 16.0f;
  gemm128<0><<<dim3(2, BL/128), 256, 0, stream>>>(hcat, 512, WqT, bq, qbuf, BL, 256, 256, qscale);
  gemm128<0><<<dim3(2, BL/128), 256, 0, stream>>>(tgtb, 256, WkT, bk, kbuf, BL, 256, 256, 1.0f);
  gemm128<1><<<dim3(2, BL/128), 256, 0, stream>>>(tgtb, 256, WvT, bv, vtbuf, BL, 256, 256, 1.0f);

  // flash attention (2 KV halves) + merge
  attn_kernel<<<dim3(LQ/128, BATCH, NHALF), 256, 0, stream>>>(qbuf, kbuf, vtbuf, opart, stats);
  merge_kernel<<<dim3(BL*32/256), 256, 0, stream>>>(opart, stats, msg);

  // output proj + LN1 -> hcat right half
  gemm128<2><<<dim3(2, BL/128), 256, 0, stream>>>(msg, 256, WmT, bm, msg2, BL, 256, 256, 1.0f);
  ln_kernel<0><<<dim3(BL/4), 256, 0, stream>>>(msg2, g1, be1, nullptr, hcat);

  // MLP: GELU(hcat @ W1) @ W2, LN2 + residual
  gemm128<3><<<dim3(4, BL/128), 256, 0, stream>>>(hcat, 512, W1T, nullptr, hact, BL, 512, 512, 1.0f);
  gemm128<2><<<dim3(2, BL/128), 256, 0, stream>>>(hact, 512, W2T, nullptr, h2, BL, 256, 512, 1.0f);
  ln_kernel<1><<<dim3(BL/4), 256, 0, stream>>>(h2, g2, be2, source, d_out);
}